// Round 6
// baseline (755.947 us; speedup 1.0000x reference)
//
#include <hip/hip_runtime.h>
#include <hip/hip_fp16.h>

#define NN 10000
#define FF 32
#define PG 4      // pairs per group
#define NGRP 24   // 96 pairs / PG

__device__ __forceinline__ unsigned short f2h(float f){
  union { unsigned short s; _Float16 h; } c; c.h = (_Float16)f; return c.s;
}

// acc.x += w * lo_f16(h); acc.y += w * hi_f16(h)  -- one VOP3P instr each.
// op_sel_hi[1]=1 marks S1 as f16; op_sel[1] picks the half. S0/S2 stay f32.
__device__ __forceinline__ void fmix2(float& ax, float& ay, float w, unsigned h){
  asm("v_fma_mix_f32 %0, %2, %3, %0 op_sel_hi:[0,1,0]\n\t"
      "v_fma_mix_f32 %1, %2, %3, %1 op_sel:[0,1,0] op_sel_hi:[0,1,0]"
      : "+v"(ax), "+v"(ay) : "v"(w), "v"(h));
}
// SGPR-weight variant for wave-uniform scalars (self-loop dinv term).
__device__ __forceinline__ void fmix2s(float& ax, float& ay, float w, unsigned h){
  asm("v_fma_mix_f32 %0, %2, %3, %0 op_sel_hi:[0,1,0]\n\t"
      "v_fma_mix_f32 %1, %2, %3, %1 op_sel:[0,1,0] op_sel_hi:[0,1,0]"
      : "+v"(ax), "+v"(ay) : "s"(w), "v"(h));
}

// ---- CSR build -------------------------------------------------------------
__global__ void k_count(const int* __restrict__ dst, int* __restrict__ cnt, int E){
  int e = blockIdx.x * 256 + threadIdx.x;
  if (e < E) atomicAdd(&cnt[dst[e]], 1);
}

// exclusive scan of PADDED counts (pad to multiple of 4); dinv from real count.
// Also computes W12 = W1@W2 and bb = b1@W2 (fused to save a dispatch).
__global__ __launch_bounds__(1024) void k_scan(const int* __restrict__ cnt,
                                               int* __restrict__ off,
                                               float* __restrict__ dinv,
                                               const float* __restrict__ W1,
                                               const float* __restrict__ W2,
                                               const float* __restrict__ b1,
                                               float* __restrict__ W12,
                                               float* __restrict__ bb){
  __shared__ int wsum[16];
  __shared__ int carry;
  int tid = threadIdx.x, lane = tid & 63, wv = tid >> 6;
  if (tid == 0) carry = 0;
  __syncthreads();
  for (int base = 0; base < NN; base += 1024){
    int i = base + tid;
    int c = (i < NN) ? cnt[i] : 0;
    int v = (c + 3) & ~3;                      // padded degree
    int s = v;
    #pragma unroll
    for (int o = 1; o < 64; o <<= 1){
      int t = __shfl_up(s, o, 64);
      if (lane >= o) s += t;
    }
    if (lane == 63) wsum[wv] = s;
    __syncthreads();
    if (tid == 0){
      int a = carry;
      #pragma unroll
      for (int k = 0; k < 16; ++k){ int t = wsum[k]; wsum[k] = a; a += t; }
      carry = a;
    }
    __syncthreads();
    if (i < NN){
      off[i]  = wsum[wv] + s - v;              // exclusive padded offset
      dinv[i] = rsqrtf((float)(c + 1));        // real degree + self loop
    }
    __syncthreads();
  }
  if (tid == 0) off[NN] = carry;
  // fused W12 / bb
  for (int idx = tid; idx < 33 * 32; idx += 1024){
    int k = idx >> 5, j = idx & 31;
    float s = 0.f;
    for (int m = 0; m < 64; ++m) s += W1[k * 64 + m] * W2[m * 32 + j];
    W12[idx] = s;
  }
  if (tid < 32){
    int j = tid;
    float s = 0.f;
    for (int m = 0; m < 64; ++m) s += b1[m] * W2[m * 32 + j];
    bb[j] = s;
  }
}

// csr entry: {row byte offset (src*256), fp32 weight dinv[src]}
// pad holes (memset 0) read row 0 with weight 0.0 -> harmless.
__global__ void k_scatter(const int* __restrict__ ei, const int* __restrict__ off,
                          int* __restrict__ cur, const float* __restrict__ dinv,
                          int2* __restrict__ csr, int E){
  int e = blockIdx.x * 256 + threadIdx.x;
  if (e >= E) return;
  int s = ei[e], d = ei[E + e];
  int pos = off[d] + atomicAdd(&cur[d], 1);
  csr[pos] = make_int2(s << 8, __float_as_int(dinv[s]));
}

// ---- s[n] = rowsum(A) ------------------------------------------------------
__global__ void k_srow(const int* __restrict__ off, const int2* __restrict__ csr,
                       const float* __restrict__ dinv, float* __restrict__ srow){
  int n = blockIdx.x * 256 + threadIdx.x;
  if (n >= NN) return;
  float a = dinv[n];
  int e0 = off[n], e1 = off[n + 1];
  for (int j = e0; j < e1; ++j) a += __int_as_float(csr[j].y);  // pads add 0
  srow[n] = dinv[n] * a;
}

// ---- GEMM1 v2: one thread = one (pg, node), all 32 features ----------------
__global__ __launch_bounds__(256) void k_gemm1(const float* __restrict__ x,
    const float* __restrict__ mask, const float* __restrict__ W12,
    unsigned* __restrict__ hw){
  const int pg = blockIdx.y;                  // 0..95 (b*24+h)
  const int n  = blockIdx.x * 256 + threadIdx.x;
  const int grp = pg >> 2, p = pg & 3;
  const float mv = mask[pg];
  float acc[32];
  #pragma unroll
  for (int f = 0; f < 32; ++f) acc[f] = mv * W12[32 * 32 + f];  // mask row
  if (n >= NN) return;
  const float4* xp = (const float4*)(x + (size_t)pg * (NN * FF) + (size_t)n * FF);
  float xv[32];
  #pragma unroll
  for (int i = 0; i < 8; ++i){
    float4 v = xp[i];
    xv[4*i]   = v.x; xv[4*i+1] = v.y;
    xv[4*i+2] = v.z; xv[4*i+3] = v.w;
  }
  #pragma unroll
  for (int k = 0; k < 32; ++k){
    const float xk = xv[k];
    #pragma unroll
    for (int f = 0; f < 32; ++f) acc[f] += xk * W12[k * 32 + f];
  }
  unsigned* hwg = hw + (size_t)grp * (NN * 64) + ((size_t)n << 6) + (p << 4);
  #pragma unroll
  for (int j = 0; j < 4; ++j){
    uint4 u;
    u.x = (unsigned)f2h(acc[8*j+0]) | ((unsigned)f2h(acc[8*j+1]) << 16);
    u.y = (unsigned)f2h(acc[8*j+2]) | ((unsigned)f2h(acc[8*j+3]) << 16);
    u.z = (unsigned)f2h(acc[8*j+4]) | ((unsigned)f2h(acc[8*j+5]) << 16);
    u.w = (unsigned)f2h(acc[8*j+6]) | ((unsigned)f2h(acc[8*j+7]) << 16);
    ((uint4*)hwg)[j] = u;
  }
}

// ---- block->group mapping: pin each group to one XCD (blockIdx%8) ----------
// One group slice (2.56 MB) per XCD at a time -> gathers stay L2-resident.
__device__ __forceinline__ void map_block(int bx, int& grp, int& chunk){
  int r  = bx / 5000;       // 0..2
  int w8 = bx % 5000;
  grp   = r * 8 + (w8 & 7);
  chunk = w8 >> 3;          // 0..624
}

// ---- 4-deep pipelined edge accumulation ------------------------------------
// KEY: csr quads are loaded as VECTOR loads at a wave-uniform address (opaque
// vz forces the offset into a VGPR). SMEM (s_load) results are out-of-order
// w.r.t. lgkmcnt on CDNA, so any scalar csr consumption forces lgkmcnt(0) --
// draining the whole scalar prefetch queue every step (incl. HBM-miss csr
// lines: csr 2.7MB x 24 walks doesn't fit L2 next to the 2.56MB V slice).
// Vector loads are vmcnt-counted IN ORDER -> the 4-quad lead is real.
__device__ __forceinline__ void agg_edges(int e0, int e1,
    const int2* __restrict__ csr, const char* __restrict__ Vb, int loff,
    float& ax, float& ay){
  int nq = (e1 - e0) >> 2;
  if (nq <= 0) return;
  const char* c4 = (const char*)(csr + e0);   // uniform SGPR base
  int vz = 0; asm("" : "+v"(vz));             // opaque 0 in a VGPR
  const int qlast = nq - 1;
  // quad i: two int4s at byte offsets 32*i and 32*i+16 (saddr-form loads)
  #define CLD(ii)  (*(const int4*)(c4 + (((ii) << 5) + vz)))
  #define CLD2(ii) (*(const int4*)(c4 + (((ii) << 5) + 16 + vz)))
  int4 cA, dA, cB, dB, cC, dC, cD, dD;          // csr for quad resident in r*
  int4 cA2, dA2, cB2, dB2, cC2, dC2, cD2, dD2;  // csr for quad+4 (gather issue)
  unsigned rA0,rA1,rA2,rA3, rB0,rB1,rB2,rB3;
  unsigned rC0,rC1,rC2,rC3, rD0,rD1,rD2,rD3;
  {
    int i1 = 1<=qlast?1:qlast, i2 = 2<=qlast?2:qlast, i3 = 3<=qlast?3:qlast;
    cA = CLD(0);   dA = CLD2(0);
    cB = CLD(i1);  dB = CLD2(i1);
    cC = CLD(i2);  dC = CLD2(i2);
    cD = CLD(i3);  dD = CLD2(i3);
    int i4 = 4<=qlast?4:qlast, i5 = 5<=qlast?5:qlast;
    int i6 = 6<=qlast?6:qlast, i7 = 7<=qlast?7:qlast;
    cA2 = CLD(i4); dA2 = CLD2(i4);
    cB2 = CLD(i5); dB2 = CLD2(i5);
    cC2 = CLD(i6); dC2 = CLD2(i6);
    cD2 = CLD(i7); dD2 = CLD2(i7);
    rA0 = *(const unsigned*)(Vb + (unsigned)(cA.x + loff));
    rA1 = *(const unsigned*)(Vb + (unsigned)(cA.z + loff));
    rA2 = *(const unsigned*)(Vb + (unsigned)(dA.x + loff));
    rA3 = *(const unsigned*)(Vb + (unsigned)(dA.z + loff));
    rB0 = *(const unsigned*)(Vb + (unsigned)(cB.x + loff));
    rB1 = *(const unsigned*)(Vb + (unsigned)(cB.z + loff));
    rB2 = *(const unsigned*)(Vb + (unsigned)(dB.x + loff));
    rB3 = *(const unsigned*)(Vb + (unsigned)(dB.z + loff));
    rC0 = *(const unsigned*)(Vb + (unsigned)(cC.x + loff));
    rC1 = *(const unsigned*)(Vb + (unsigned)(cC.z + loff));
    rC2 = *(const unsigned*)(Vb + (unsigned)(dC.x + loff));
    rC3 = *(const unsigned*)(Vb + (unsigned)(dC.z + loff));
    rD0 = *(const unsigned*)(Vb + (unsigned)(cD.x + loff));
    rD1 = *(const unsigned*)(Vb + (unsigned)(cD.z + loff));
    rD2 = *(const unsigned*)(Vb + (unsigned)(dD.x + loff));
    rD3 = *(const unsigned*)(Vb + (unsigned)(dD.z + loff));
  }
  int q = 0;
  #define AGG_STEP(cX, dX, cX2, dX2, r0, r1, r2, r3, LEAD)              \
    do {                                                                \
      fmix2(ax, ay, __int_as_float(cX.y), r0);                          \
      fmix2(ax, ay, __int_as_float(cX.w), r1);                          \
      fmix2(ax, ay, __int_as_float(dX.y), r2);                          \
      fmix2(ax, ay, __int_as_float(dX.w), r3);                          \
      r0 = *(const unsigned*)(Vb + (unsigned)(cX2.x + loff));           \
      r1 = *(const unsigned*)(Vb + (unsigned)(cX2.z + loff));           \
      r2 = *(const unsigned*)(Vb + (unsigned)(dX2.x + loff));           \
      r3 = *(const unsigned*)(Vb + (unsigned)(dX2.z + loff));           \
      cX = cX2; dX = dX2;                                               \
      int ii = q + (LEAD); ii = ii <= qlast ? ii : qlast;               \
      cX2 = CLD(ii); dX2 = CLD2(ii);                                    \
    } while (0)
  for (; q + 3 < nq; q += 4){
    AGG_STEP(cA,dA,cA2,dA2, rA0,rA1,rA2,rA3, 8);
    AGG_STEP(cB,dB,cB2,dB2, rB0,rB1,rB2,rB3, 9);
    AGG_STEP(cC,dC,cC2,dC2, rC0,rC1,rC2,rC3, 10);
    AGG_STEP(cD,dD,cD2,dD2, rD0,rD1,rD2,rD3, 11);
  }
  #undef AGG_STEP
  #undef CLD
  #undef CLD2
  int rem = nq - q;   // 0..3 (wave-uniform)
  if (rem > 0){
    fmix2(ax, ay, __int_as_float(cA.y), rA0);
    fmix2(ax, ay, __int_as_float(cA.w), rA1);
    fmix2(ax, ay, __int_as_float(dA.y), rA2);
    fmix2(ax, ay, __int_as_float(dA.w), rA3);
  }
  if (rem > 1){
    fmix2(ax, ay, __int_as_float(cB.y), rB0);
    fmix2(ax, ay, __int_as_float(cB.w), rB1);
    fmix2(ax, ay, __int_as_float(dB.y), rB2);
    fmix2(ax, ay, __int_as_float(dB.w), rB3);
  }
  if (rem > 2){
    fmix2(ax, ay, __int_as_float(cC.y), rC0);
    fmix2(ax, ay, __int_as_float(cC.w), rC1);
    fmix2(ax, ay, __int_as_float(dC.y), rC2);
    fmix2(ax, ay, __int_as_float(dC.w), rC3);
  }
}

// ---- agg layer 1: t1 = A*hw (fp16 rows, fp32 accum) ------------------------
__global__ __launch_bounds__(256) void k_agg1(const int* __restrict__ off,
    const int2* __restrict__ csr, const float* __restrict__ dinv,
    const unsigned int* __restrict__ V, unsigned int* __restrict__ T){
  int grp, chunk; map_block(blockIdx.x, grp, chunk);
  int tid = threadIdx.x;
  int l = tid & 63;
  int wv = __builtin_amdgcn_readfirstlane(tid) >> 6;   // wave-uniform
  const char* Vb = (const char*)(V + (size_t)grp * (NN * 64));
  unsigned int* Tg = T + (size_t)grp * (NN * 64);
  int loff = l * 4;
  for (int it = 0; it < 4; ++it){
    int n = chunk * 16 + wv * 4 + it;
    float din = dinv[n];
    int e0 = off[n], e1 = off[n + 1];
    unsigned sv = *(const unsigned*)(Vb + (unsigned)((n << 8) + loff));
    float ax = 0.f, ay = 0.f;
    fmix2s(ax, ay, din, sv);
    agg_edges(e0, e1, csr, Vb, loff, ax, ay);
    Tg[((size_t)n << 6) + l] =
        (unsigned)f2h(din * ax) | ((unsigned)f2h(din * ay) << 16);
  }
}

// ---- agg layer 2 + epilogue: out = tanh(A*t1 + srow*bb + b2) fp32 ----------
__global__ __launch_bounds__(256) void k_agg2(const int* __restrict__ off,
    const int2* __restrict__ csr, const float* __restrict__ dinv,
    const float* __restrict__ srow, const float* __restrict__ bb,
    const float* __restrict__ b2, const unsigned int* __restrict__ V,
    float* __restrict__ out){
  int grp, chunk; map_block(blockIdx.x, grp, chunk);
  int tid = threadIdx.x;
  int l = tid & 63;
  int wv = __builtin_amdgcn_readfirstlane(tid) >> 6;
  int p = l >> 4, fi = l & 15;
  const char* Vb = (const char*)(V + (size_t)grp * (NN * 64));
  int pg = grp * PG + p;
  float2 bbq = ((const float2*)bb)[fi];
  float2 b2q = ((const float2*)b2)[fi];
  float* outp = out + (size_t)pg * (NN * FF);
  int loff = l * 4;
  for (int it = 0; it < 4; ++it){
    int n = chunk * 16 + wv * 4 + it;
    float din = dinv[n];
    int e0 = off[n], e1 = off[n + 1];
    unsigned sv = *(const unsigned*)(Vb + (unsigned)((n << 8) + loff));
    float ax = 0.f, ay = 0.f;
    fmix2s(ax, ay, din, sv);
    agg_edges(e0, e1, csr, Vb, loff, ax, ay);
    float sr = srow[n];
    float2 o;
    o.x = tanhf(din * ax + sr * bbq.x + b2q.x);
    o.y = tanhf(din * ay + sr * bbq.y + b2q.y);
    ((float2*)(outp + (size_t)n * FF))[fi] = o;
  }
}

extern "C" void kernel_launch(void* const* d_in, const int* in_sizes, int n_in,
                              void* d_out, int out_size, void* d_ws, size_t ws_size,
                              hipStream_t stream){
  const float* x    = (const float*)d_in[0];
  const float* mask = (const float*)d_in[1];
  const int*   ei   = (const int*)d_in[2];
  const float* W1   = (const float*)d_in[3];
  const float* b1   = (const float*)d_in[4];
  const float* W2   = (const float*)d_in[5];
  const float* b2   = (const float*)d_in[6];
  float* out = (float*)d_out;
  const int E = in_sizes[2] / 2;   // 320000
  const int CSRCAP = E + 3 * NN + 64;  // padded-to-4 worst case + overread slack

  char* wsp = (char*)d_ws;
  auto alloc = [&](size_t bytes) -> char* {
    char* p = wsp; wsp += (bytes + 255) & ~(size_t)255; return p;
  };
  int*   cnt  = (int*)  alloc((size_t)NN * 4);
  int*   off  = (int*)  alloc((size_t)(NN + 1) * 4);
  int*   cur  = (int*)  alloc((size_t)NN * 4);
  float* dinv = (float*)alloc((size_t)NN * 4);
  float* srow = (float*)alloc((size_t)NN * 4);
  float* W12  = (float*)alloc(33 * 32 * 4);
  float* bbv  = (float*)alloc(32 * 4);
  int2*  csr  = (int2*) alloc((size_t)CSRCAP * 8);
  const size_t per_group = (size_t)NN * 64 * 4;    // [n][4p][32f] fp16 = 2.56MB
  unsigned int* hw = (unsigned int*)alloc((size_t)NGRP * per_group);
  unsigned int* t1 = (unsigned int*)alloc((size_t)NGRP * per_group);

  hipMemsetAsync(cnt, 0, (size_t)NN * 4, stream);
  hipMemsetAsync(cur, 0, (size_t)NN * 4, stream);
  hipMemsetAsync(csr, 0, (size_t)CSRCAP * 8, stream);   // pad entries: row 0, w=0
  k_count  <<<(E + 255) / 256, 256, 0, stream>>>(ei + E, cnt, E);
  k_scan   <<<1, 1024, 0, stream>>>(cnt, off, dinv, W1, W2, b1, W12, bbv);
  k_scatter<<<(E + 255) / 256, 256, 0, stream>>>(ei, off, cur, dinv, csr, E);
  k_srow   <<<(NN + 255) / 256, 256, 0, stream>>>(off, csr, dinv, srow);

  k_gemm1<<<dim3(40, 96), 256, 0, stream>>>(x, mask, W12, hw);
  k_agg1 <<<15000, 256, 0, stream>>>(off, csr, dinv, hw, t1);
  k_agg2 <<<15000, 256, 0, stream>>>(off, csr, dinv, srow, bbv, b2, t1, out);
}

// Round 7
// 513.434 us; speedup vs baseline: 1.4723x; 1.4723x over previous
//
#include <hip/hip_runtime.h>
#include <hip/hip_fp16.h>

#define NN 10000
#define FF 32
#define PG 4      // pairs per group
#define NGRP 24   // 96 pairs / PG

typedef __attribute__((ext_vector_type(2))) float f32x2;

__device__ __forceinline__ unsigned short f2h(float f){
  union { unsigned short s; _Float16 h; } c; c.h = (_Float16)f; return c.s;
}

// acc.x += w * lo_f16(h); acc.y += w * hi_f16(h)  -- one VOP3P instr each.
// op_sel_hi[1]=1 marks S1 as f16; op_sel[1] picks the half. S0/S2 stay f32.
__device__ __forceinline__ void fmix2(float& ax, float& ay, float w, unsigned h){
  asm("v_fma_mix_f32 %0, %2, %3, %0 op_sel_hi:[0,1,0]\n\t"
      "v_fma_mix_f32 %1, %2, %3, %1 op_sel:[0,1,0] op_sel_hi:[0,1,0]"
      : "+v"(ax), "+v"(ay) : "v"(w), "v"(h));
}

// packed fp32 FMA: acc += w * x (elementwise float2). CDNA4's 157 TF fp32
// peak is only reachable via v_pk_fma_f32 (scalar v_fma = half rate).
// w is wave-uniform -> SGPR pair (VOP3P allows 1 scalar source; proven on
// this toolchain by the fma_mix "s" variant in round 5).
__device__ __forceinline__ void pkfma(f32x2& acc, f32x2 w, f32x2 x){
  asm("v_pk_fma_f32 %0, %1, %2, %0" : "+v"(acc) : "s"(w), "v"(x));
}

// ---- CSR build -------------------------------------------------------------
// Also zeroes the padded csr array (folds the 2.9 MB memset dispatch).
__global__ void k_count(const int* __restrict__ dst, int* __restrict__ cnt,
                        int2* __restrict__ csr, int csrcap, int E){
  int e = blockIdx.x * 256 + threadIdx.x;
  if (e >= E) return;
  csr[e] = make_int2(0, 0);
  int e2 = e + E;
  if (e2 < csrcap) csr[e2] = make_int2(0, 0);
  atomicAdd(&cnt[dst[e]], 1);
}

// exclusive scan of PADDED counts (pad to multiple of 4); dinv from real count.
// Also computes W12 = W1@W2 and bb = b1@W2 (fused to save a dispatch).
__global__ __launch_bounds__(1024) void k_scan(const int* __restrict__ cnt,
                                               int* __restrict__ off,
                                               float* __restrict__ dinv,
                                               const float* __restrict__ W1,
                                               const float* __restrict__ W2,
                                               const float* __restrict__ b1,
                                               float* __restrict__ W12,
                                               float* __restrict__ bb){
  __shared__ int wsum[16];
  __shared__ int carry;
  int tid = threadIdx.x, lane = tid & 63, wv = tid >> 6;
  if (tid == 0) carry = 0;
  __syncthreads();
  for (int base = 0; base < NN; base += 1024){
    int i = base + tid;
    int c = (i < NN) ? cnt[i] : 0;
    int v = (c + 3) & ~3;                      // padded degree
    int s = v;
    #pragma unroll
    for (int o = 1; o < 64; o <<= 1){
      int t = __shfl_up(s, o, 64);
      if (lane >= o) s += t;
    }
    if (lane == 63) wsum[wv] = s;
    __syncthreads();
    if (tid == 0){
      int a = carry;
      #pragma unroll
      for (int k = 0; k < 16; ++k){ int t = wsum[k]; wsum[k] = a; a += t; }
      carry = a;
    }
    __syncthreads();
    if (i < NN){
      off[i]  = wsum[wv] + s - v;              // exclusive padded offset
      dinv[i] = rsqrtf((float)(c + 1));        // real degree + self loop
    }
    __syncthreads();
  }
  if (tid == 0) off[NN] = carry;
  // fused W12 / bb
  for (int idx = tid; idx < 33 * 32; idx += 1024){
    int k = idx >> 5, j = idx & 31;
    float s = 0.f;
    for (int m = 0; m < 64; ++m) s += W1[k * 64 + m] * W2[m * 32 + j];
    W12[idx] = s;
  }
  if (tid < 32){
    int j = tid;
    float s = 0.f;
    for (int m = 0; m < 64; ++m) s += b1[m] * W2[m * 32 + j];
    bb[j] = s;
  }
}

// csr entry: {row byte offset (src*256), fp32 weight dinv[src]}
// pad holes (zeroed in k_count) read row 0 with weight 0.0 -> harmless.
// Also accumulates srow_acc[d] = sum of dinv[src] (replaces the k_srow pass;
// agg2 reconstructs srow = dinv*(dinv+acc)).
__global__ void k_scatter(const int* __restrict__ ei, const int* __restrict__ off,
                          int* __restrict__ cur, const float* __restrict__ dinv,
                          int2* __restrict__ csr, float* __restrict__ srow, int E){
  int e = blockIdx.x * 256 + threadIdx.x;
  if (e >= E) return;
  int s = ei[e], d = ei[E + e];
  float ds = dinv[s];
  int pos = off[d] + atomicAdd(&cur[d], 1);
  csr[pos] = make_int2(s << 8, __float_as_int(ds));
  atomicAdd(&srow[d], ds);
}

// ---- GEMM1 v3: one thread = one (pg, node); packed-fp32 math ---------------
__global__ __launch_bounds__(256) void k_gemm1(const float* __restrict__ x,
    const float* __restrict__ mask, const float* __restrict__ W12,
    unsigned* __restrict__ hw){
  const int pg = blockIdx.y;                  // 0..95 (b*24+h)
  const int n  = blockIdx.x * 256 + threadIdx.x;
  const int grp = pg >> 2, p = pg & 3;
  const float mv = mask[pg];
  const f32x2* Wp = (const f32x2*)W12;        // [33][16] feature pairs
  f32x2 acc[16];
  #pragma unroll
  for (int qf = 0; qf < 16; ++qf){
    f32x2 w = Wp[32 * 16 + qf];               // mask row
    acc[qf].x = mv * w.x; acc[qf].y = mv * w.y;
  }
  if (n >= NN) return;
  const float4* xp = (const float4*)(x + (size_t)pg * (NN * FF) + (size_t)n * FF);
  float xv[32];
  #pragma unroll
  for (int i = 0; i < 8; ++i){
    float4 v = xp[i];
    xv[4*i]   = v.x; xv[4*i+1] = v.y;
    xv[4*i+2] = v.z; xv[4*i+3] = v.w;
  }
  #pragma unroll
  for (int k = 0; k < 32; ++k){
    f32x2 xk2; xk2.x = xv[k]; xk2.y = xv[k];
    #pragma unroll
    for (int qf = 0; qf < 16; ++qf) pkfma(acc[qf], Wp[k * 16 + qf], xk2);
  }
  unsigned* hwg = hw + (size_t)grp * (NN * 64) + ((size_t)n << 6) + (p << 4);
  #pragma unroll
  for (int j = 0; j < 4; ++j){
    uint4 u;
    u.x = (unsigned)f2h(acc[4*j+0].x) | ((unsigned)f2h(acc[4*j+0].y) << 16);
    u.y = (unsigned)f2h(acc[4*j+1].x) | ((unsigned)f2h(acc[4*j+1].y) << 16);
    u.z = (unsigned)f2h(acc[4*j+2].x) | ((unsigned)f2h(acc[4*j+2].y) << 16);
    u.w = (unsigned)f2h(acc[4*j+3].x) | ((unsigned)f2h(acc[4*j+3].y) << 16);
    ((uint4*)hwg)[j] = u;
  }
}

// ---- block->group mapping: pin each group to one XCD (blockIdx%8) ----------
// One group slice (2.56 MB) per XCD at a time -> gathers stay L2-resident.
__device__ __forceinline__ void map_block(int bx, int& grp, int& chunk){
  int r  = bx / 5000;       // 0..2
  int w8 = bx % 5000;
  grp   = r * 8 + (w8 & 7);
  chunk = w8 >> 3;          // 0..624
}

// ---- 4-deep pipelined edge accumulation (round-4 best, verbatim) -----------
__device__ __forceinline__ void agg_edges(int e0, int e1,
    const int2* __restrict__ csr, const char* __restrict__ Vb, int loff,
    float& ax, float& ay){
  int nq = (e1 - e0) >> 2;
  if (nq <= 0) return;
  const int4* c4 = (const int4*)(csr + e0);
  const int qlast = nq - 1;
  int4 cA, dA, cB, dB, cC, dC, cD, dD;          // csr for quad resident in r*
  int4 cA2, dA2, cB2, dB2, cC2, dC2, cD2, dD2;  // csr for quad+4 (gather issue)
  unsigned rA0,rA1,rA2,rA3, rB0,rB1,rB2,rB3;
  unsigned rC0,rC1,rC2,rC3, rD0,rD1,rD2,rD3;
  {
    int i1 = 1<=qlast?1:qlast, i2 = 2<=qlast?2:qlast, i3 = 3<=qlast?3:qlast;
    cA = c4[0];      dA = c4[1];
    cB = c4[2*i1];   dB = c4[2*i1+1];
    cC = c4[2*i2];   dC = c4[2*i2+1];
    cD = c4[2*i3];   dD = c4[2*i3+1];
    int i4 = 4<=qlast?4:qlast, i5 = 5<=qlast?5:qlast;
    int i6 = 6<=qlast?6:qlast, i7 = 7<=qlast?7:qlast;
    cA2 = c4[2*i4];  dA2 = c4[2*i4+1];
    cB2 = c4[2*i5];  dB2 = c4[2*i5+1];
    cC2 = c4[2*i6];  dC2 = c4[2*i6+1];
    cD2 = c4[2*i7];  dD2 = c4[2*i7+1];
    rA0 = *(const unsigned*)(Vb + (unsigned)(cA.x + loff));
    rA1 = *(const unsigned*)(Vb + (unsigned)(cA.z + loff));
    rA2 = *(const unsigned*)(Vb + (unsigned)(dA.x + loff));
    rA3 = *(const unsigned*)(Vb + (unsigned)(dA.z + loff));
    rB0 = *(const unsigned*)(Vb + (unsigned)(cB.x + loff));
    rB1 = *(const unsigned*)(Vb + (unsigned)(cB.z + loff));
    rB2 = *(const unsigned*)(Vb + (unsigned)(dB.x + loff));
    rB3 = *(const unsigned*)(Vb + (unsigned)(dB.z + loff));
    rC0 = *(const unsigned*)(Vb + (unsigned)(cC.x + loff));
    rC1 = *(const unsigned*)(Vb + (unsigned)(cC.z + loff));
    rC2 = *(const unsigned*)(Vb + (unsigned)(dC.x + loff));
    rC3 = *(const unsigned*)(Vb + (unsigned)(dC.z + loff));
    rD0 = *(const unsigned*)(Vb + (unsigned)(cD.x + loff));
    rD1 = *(const unsigned*)(Vb + (unsigned)(cD.z + loff));
    rD2 = *(const unsigned*)(Vb + (unsigned)(dD.x + loff));
    rD3 = *(const unsigned*)(Vb + (unsigned)(dD.z + loff));
  }
  int q = 0;
  #define AGG_STEP(cX, dX, cX2, dX2, r0, r1, r2, r3, LEAD)              \
    do {                                                                \
      fmix2(ax, ay, __int_as_float(cX.y), r0);                          \
      fmix2(ax, ay, __int_as_float(cX.w), r1);                          \
      fmix2(ax, ay, __int_as_float(dX.y), r2);                          \
      fmix2(ax, ay, __int_as_float(dX.w), r3);                          \
      r0 = *(const unsigned*)(Vb + (unsigned)(cX2.x + loff));           \
      r1 = *(const unsigned*)(Vb + (unsigned)(cX2.z + loff));           \
      r2 = *(const unsigned*)(Vb + (unsigned)(dX2.x + loff));           \
      r3 = *(const unsigned*)(Vb + (unsigned)(dX2.z + loff));           \
      cX = cX2; dX = dX2;                                               \
      int ii = q + (LEAD); ii = ii <= qlast ? ii : qlast;               \
      cX2 = c4[2*ii]; dX2 = c4[2*ii+1];                                 \
    } while (0)
  for (; q + 3 < nq; q += 4){
    AGG_STEP(cA,dA,cA2,dA2, rA0,rA1,rA2,rA3, 8);
    AGG_STEP(cB,dB,cB2,dB2, rB0,rB1,rB2,rB3, 9);
    AGG_STEP(cC,dC,cC2,dC2, rC0,rC1,rC2,rC3, 10);
    AGG_STEP(cD,dD,cD2,dD2, rD0,rD1,rD2,rD3, 11);
  }
  #undef AGG_STEP
  int rem = nq - q;   // 0..3 (wave-uniform)
  if (rem > 0){
    fmix2(ax, ay, __int_as_float(cA.y), rA0);
    fmix2(ax, ay, __int_as_float(cA.w), rA1);
    fmix2(ax, ay, __int_as_float(dA.y), rA2);
    fmix2(ax, ay, __int_as_float(dA.w), rA3);
  }
  if (rem > 1){
    fmix2(ax, ay, __int_as_float(cB.y), rB0);
    fmix2(ax, ay, __int_as_float(cB.w), rB1);
    fmix2(ax, ay, __int_as_float(dB.y), rB2);
    fmix2(ax, ay, __int_as_float(dB.w), rB3);
  }
  if (rem > 2){
    fmix2(ax, ay, __int_as_float(cC.y), rC0);
    fmix2(ax, ay, __int_as_float(cC.w), rC1);
    fmix2(ax, ay, __int_as_float(dC.y), rC2);
    fmix2(ax, ay, __int_as_float(dC.w), rC3);
  }
}

// ---- agg layer 1: t1 = A*hw (fp16 rows, fp32 accum) ------------------------
__global__ __launch_bounds__(256) void k_agg1(const int* __restrict__ off,
    const int2* __restrict__ csr, const float* __restrict__ dinv,
    const unsigned int* __restrict__ V, unsigned int* __restrict__ T){
  int grp, chunk; map_block(blockIdx.x, grp, chunk);
  int tid = threadIdx.x;
  int l = tid & 63;
  int wv = __builtin_amdgcn_readfirstlane(tid) >> 6;   // wave-uniform
  const char* Vb = (const char*)(V + (size_t)grp * (NN * 64));
  unsigned int* Tg = T + (size_t)grp * (NN * 64);
  int loff = l * 4;
  for (int it = 0; it < 4; ++it){
    int n = chunk * 16 + wv * 4 + it;
    float din = dinv[n];
    int e0 = off[n], e1 = off[n + 1];
    unsigned sv = *(const unsigned*)(Vb + (unsigned)((n << 8) + loff));
    union { unsigned u; _Float16 h[2]; } cv; cv.u = sv;
    float ax = din * (float)cv.h[0];
    float ay = din * (float)cv.h[1];
    agg_edges(e0, e1, csr, Vb, loff, ax, ay);
    Tg[((size_t)n << 6) + l] =
        (unsigned)f2h(din * ax) | ((unsigned)f2h(din * ay) << 16);
  }
}

// ---- agg layer 2 + epilogue: out = tanh(A*t1 + srow*bb + b2) fp32 ----------
__global__ __launch_bounds__(256) void k_agg2(const int* __restrict__ off,
    const int2* __restrict__ csr, const float* __restrict__ dinv,
    const float* __restrict__ srow, const float* __restrict__ bb,
    const float* __restrict__ b2, const unsigned int* __restrict__ V,
    float* __restrict__ out){
  int grp, chunk; map_block(blockIdx.x, grp, chunk);
  int tid = threadIdx.x;
  int l = tid & 63;
  int wv = __builtin_amdgcn_readfirstlane(tid) >> 6;
  int p = l >> 4, fi = l & 15;
  const char* Vb = (const char*)(V + (size_t)grp * (NN * 64));
  int pg = grp * PG + p;
  float2 bbq = ((const float2*)bb)[fi];
  float2 b2q = ((const float2*)b2)[fi];
  float* outp = out + (size_t)pg * (NN * FF);
  int loff = l * 4;
  for (int it = 0; it < 4; ++it){
    int n = chunk * 16 + wv * 4 + it;
    float din = dinv[n];
    int e0 = off[n], e1 = off[n + 1];
    unsigned sv = *(const unsigned*)(Vb + (unsigned)((n << 8) + loff));
    union { unsigned u; _Float16 h[2]; } cv; cv.u = sv;
    float ax = din * (float)cv.h[0];
    float ay = din * (float)cv.h[1];
    agg_edges(e0, e1, csr, Vb, loff, ax, ay);
    float sr = din * (din + srow[n]);   // srow reconstructed from scatter acc
    float2 o;
    o.x = tanhf(din * ax + sr * bbq.x + b2q.x);
    o.y = tanhf(din * ay + sr * bbq.y + b2q.y);
    ((float2*)(outp + (size_t)n * FF))[fi] = o;
  }
}

extern "C" void kernel_launch(void* const* d_in, const int* in_sizes, int n_in,
                              void* d_out, int out_size, void* d_ws, size_t ws_size,
                              hipStream_t stream){
  const float* x    = (const float*)d_in[0];
  const float* mask = (const float*)d_in[1];
  const int*   ei   = (const int*)d_in[2];
  const float* W1   = (const float*)d_in[3];
  const float* b1   = (const float*)d_in[4];
  const float* W2   = (const float*)d_in[5];
  const float* b2   = (const float*)d_in[6];
  float* out = (float*)d_out;
  const int E = in_sizes[2] / 2;   // 320000
  const int CSRCAP = E + 3 * NN + 64;  // padded-to-4 worst case + overread slack

  char* wsp = (char*)d_ws;
  auto alloc = [&](size_t bytes) -> char* {
    char* p = wsp; wsp += (bytes + 255) & ~(size_t)255; return p;
  };
  // zero-span buffers first (cnt..srow zeroed by ONE memset)
  int*   cnt  = (int*)  alloc((size_t)NN * 4);
  int*   off  = (int*)  alloc((size_t)(NN + 1) * 4);
  int*   cur  = (int*)  alloc((size_t)NN * 4);
  float* srow = (float*)alloc((size_t)NN * 4);
  float* dinv = (float*)alloc((size_t)NN * 4);
  float* W12  = (float*)alloc(33 * 32 * 4);
  float* bbv  = (float*)alloc(32 * 4);
  int2*  csr  = (int2*) alloc((size_t)CSRCAP * 8);
  const size_t per_group = (size_t)NN * 64 * 4;    // [n][4p][32f] fp16 = 2.56MB
  unsigned int* hw = (unsigned int*)alloc((size_t)NGRP * per_group);
  unsigned int* t1 = (unsigned int*)alloc((size_t)NGRP * per_group);

  size_t zspan = (size_t)((char*)dinv - (char*)cnt);
  hipMemsetAsync(cnt, 0, zspan, stream);               // cnt+off+cur+srow
  k_count  <<<(E + 255) / 256, 256, 0, stream>>>(ei + E, cnt, csr, CSRCAP, E);
  k_scan   <<<1, 1024, 0, stream>>>(cnt, off, dinv, W1, W2, b1, W12, bbv);
  k_scatter<<<(E + 255) / 256, 256, 0, stream>>>(ei, off, cur, dinv, csr, srow, E);

  k_gemm1<<<dim3(40, 96), 256, 0, stream>>>(x, mask, W12, hw);
  k_agg1 <<<15000, 256, 0, stream>>>(off, csr, dinv, hw, t1);
  k_agg2 <<<15000, 256, 0, stream>>>(off, csr, dinv, srow, bbv, b2, t1, out);
}

// Round 8
// 495.725 us; speedup vs baseline: 1.5249x; 1.0357x over previous
//
#include <hip/hip_runtime.h>
#include <hip/hip_fp16.h>

#define NN 10000
#define FF 32
#define PG 4      // pairs per group
#define NGRP 24   // 96 pairs / PG

typedef __attribute__((ext_vector_type(2))) float f32x2;

__device__ __forceinline__ unsigned short f2h(float f){
  union { unsigned short s; _Float16 h; } c; c.h = (_Float16)f; return c.s;
}

// acc += w(f16, lo half of packed SGPR word) * halves of h. One VOP3P each.
// op_sel_hi:[1,1,0] marks S0 AND S1 as f16; op_sel[1] picks S1's half.
// S0 = wave-uniform packed csr word -> SGPR operand, zero VALU for weights.
__device__ __forceinline__ void fmix2p(float& ax, float& ay, unsigned wpk, unsigned h){
  asm("v_fma_mix_f32 %0, %2, %3, %0 op_sel_hi:[1,1,0]\n\t"
      "v_fma_mix_f32 %1, %2, %3, %1 op_sel:[0,1,0] op_sel_hi:[1,1,0]"
      : "+v"(ax), "+v"(ay) : "s"(wpk), "v"(h));
}
// f32 SGPR weight variant (self-loop dinv term).
__device__ __forceinline__ void fmix2s(float& ax, float& ay, float w, unsigned h){
  asm("v_fma_mix_f32 %0, %2, %3, %0 op_sel_hi:[0,1,0]\n\t"
      "v_fma_mix_f32 %1, %2, %3, %1 op_sel:[0,1,0] op_sel_hi:[0,1,0]"
      : "+v"(ax), "+v"(ay) : "s"(w), "v"(h));
}

// packed fp32 FMA for gemm1 (157 TF fp32 peak needs v_pk_fma_f32).
__device__ __forceinline__ void pkfma(f32x2& acc, f32x2 w, f32x2 x){
  asm("v_pk_fma_f32 %0, %1, %2, %0" : "+v"(acc) : "s"(w), "v"(x));
}

// ---- CSR build -------------------------------------------------------------
// csr entry (u32): (src << 16) | fp16(dinv[src]). Zeroed here: pad entries
// read row 0 with weight 0.0 -> harmless. 4 B/edge -> csr 1.4 MB, fits L2
// next to the 2.56 MB V slice.
__global__ void k_count(const int* __restrict__ dst, int* __restrict__ cnt,
                        unsigned* __restrict__ csr, int csrcap, int E){
  int e = blockIdx.x * 256 + threadIdx.x;
  if (e >= E) return;
  csr[e] = 0u;
  int e2 = e + E;
  if (e2 < csrcap) csr[e2] = 0u;
  atomicAdd(&cnt[dst[e]], 1);
}

// Parallel prep (replaces the single-block serial scan): offsets allocated
// via unordered atomicAdd (CSR row order is irrelevant -- ranges just need
// to be disjoint); stores {start,end} so aggs still do one s_load_dwordx2.
// Blocks 40..44 compute W12 = W1@W2 and bb = b1@W2.
__global__ __launch_bounds__(256) void k_prep(const int* __restrict__ cnt,
    int2* __restrict__ oe, float* __restrict__ dinv, int* __restrict__ gtop,
    const float* __restrict__ W1, const float* __restrict__ W2,
    const float* __restrict__ b1, float* __restrict__ W12, float* __restrict__ bb){
  int bx = blockIdx.x, tid = threadIdx.x;
  if (bx < 40){
    int i = bx * 256 + tid;
    if (i < NN){
      int c = cnt[i];
      int pad = (c + 3) & ~3;
      int start = atomicAdd(gtop, pad);
      oe[i] = make_int2(start, start + pad);
      dinv[i] = rsqrtf((float)(c + 1));
    }
  } else {
    int j = (bx - 40) * 256 + tid;
    if (j < 33 * 32){
      int k = j >> 5, c = j & 31;
      float s = 0.f;
      for (int m = 0; m < 64; ++m) s += W1[k * 64 + m] * W2[m * 32 + c];
      W12[j] = s;
    } else if (j < 33 * 32 + 32){
      int c = j - 33 * 32;
      float s = 0.f;
      for (int m = 0; m < 64; ++m) s += b1[m] * W2[m * 32 + c];
      bb[c] = s;
    }
  }
}

// Also accumulates srow_acc[d] = sum of dinv[src] (agg2 reconstructs
// srow = dinv*(dinv+acc)).
__global__ void k_scatter(const int* __restrict__ ei, const int2* __restrict__ oe,
                          int* __restrict__ cur, const float* __restrict__ dinv,
                          unsigned* __restrict__ csr, float* __restrict__ srow, int E){
  int e = blockIdx.x * 256 + threadIdx.x;
  if (e >= E) return;
  int s = ei[e], d = ei[E + e];
  float ds = dinv[s];
  int pos = oe[d].x + atomicAdd(&cur[d], 1);
  csr[pos] = ((unsigned)s << 16) | (unsigned)f2h(ds);
  atomicAdd(&srow[d], ds);
}

// ---- GEMM1: one thread = one (pg, node); packed-fp32 math ------------------
__global__ __launch_bounds__(256) void k_gemm1(const float* __restrict__ x,
    const float* __restrict__ mask, const float* __restrict__ W12,
    unsigned* __restrict__ hw){
  const int pg = blockIdx.y;                  // 0..95 (b*24+h)
  const int n  = blockIdx.x * 256 + threadIdx.x;
  const int grp = pg >> 2, p = pg & 3;
  const float mv = mask[pg];
  const f32x2* Wp = (const f32x2*)W12;        // [33][16] feature pairs
  f32x2 acc[16];
  #pragma unroll
  for (int qf = 0; qf < 16; ++qf){
    f32x2 w = Wp[32 * 16 + qf];               // mask row
    acc[qf].x = mv * w.x; acc[qf].y = mv * w.y;
  }
  if (n >= NN) return;
  const float4* xp = (const float4*)(x + (size_t)pg * (NN * FF) + (size_t)n * FF);
  float xv[32];
  #pragma unroll
  for (int i = 0; i < 8; ++i){
    float4 v = xp[i];
    xv[4*i]   = v.x; xv[4*i+1] = v.y;
    xv[4*i+2] = v.z; xv[4*i+3] = v.w;
  }
  #pragma unroll
  for (int k = 0; k < 32; ++k){
    f32x2 xk2; xk2.x = xv[k]; xk2.y = xv[k];
    #pragma unroll
    for (int qf = 0; qf < 16; ++qf) pkfma(acc[qf], Wp[k * 16 + qf], xk2);
  }
  unsigned* hwg = hw + (size_t)grp * (NN * 64) + ((size_t)n << 6) + (p << 4);
  #pragma unroll
  for (int j = 0; j < 4; ++j){
    uint4 u;
    u.x = (unsigned)f2h(acc[4*j+0].x) | ((unsigned)f2h(acc[4*j+0].y) << 16);
    u.y = (unsigned)f2h(acc[4*j+1].x) | ((unsigned)f2h(acc[4*j+1].y) << 16);
    u.z = (unsigned)f2h(acc[4*j+2].x) | ((unsigned)f2h(acc[4*j+2].y) << 16);
    u.w = (unsigned)f2h(acc[4*j+3].x) | ((unsigned)f2h(acc[4*j+3].y) << 16);
    ((uint4*)hwg)[j] = u;
  }
}

// ---- block->group mapping: pin each group to one XCD (blockIdx%8) ----------
__device__ __forceinline__ void map_block(int bx, int& grp, int& chunk){
  int r  = bx / 5000;       // 0..2
  int w8 = bx % 5000;
  grp   = r * 8 + (w8 & 7);
  chunk = w8 >> 3;          // 0..624
}

// ---- 4-deep pipelined edge accumulation, packed csr ------------------------
// Per quad: 1 s_load_dwordx4 (4 edges), row byte = (w>>8)&0xFFFF00 (SALU),
// weight = f16 lo half consumed directly by fma_mix (SGPR op), 4 gathers,
// 8 fma_mix + 4 v_add. Gathers lead compute by 4 quads, csr by 8.
#define ROWB(w) ((((unsigned)(w)) >> 8) & 0xFFFF00u)
__device__ __forceinline__ void agg_edges(int e0, int e1,
    const unsigned* __restrict__ csr, const char* __restrict__ Vb, int loff,
    float& ax, float& ay){
  int nq = (e1 - e0) >> 2;
  if (nq <= 0) return;
  const int4* c4 = (const int4*)(csr + e0);   // 16 B per quad
  const int qlast = nq - 1;
  #define VLD(w) (*(const unsigned*)(Vb + (unsigned)(ROWB(w) + loff)))
  int4 cA, cB, cC, cD;          // csr for quad resident in r*
  int4 cA2, cB2, cC2, cD2;      // csr for quad+4 (gather issue)
  unsigned rA0,rA1,rA2,rA3, rB0,rB1,rB2,rB3;
  unsigned rC0,rC1,rC2,rC3, rD0,rD1,rD2,rD3;
  {
    int i1 = 1<=qlast?1:qlast, i2 = 2<=qlast?2:qlast, i3 = 3<=qlast?3:qlast;
    cA = c4[0]; cB = c4[i1]; cC = c4[i2]; cD = c4[i3];
    int i4 = 4<=qlast?4:qlast, i5 = 5<=qlast?5:qlast;
    int i6 = 6<=qlast?6:qlast, i7 = 7<=qlast?7:qlast;
    cA2 = c4[i4]; cB2 = c4[i5]; cC2 = c4[i6]; cD2 = c4[i7];
    rA0 = VLD(cA.x); rA1 = VLD(cA.y); rA2 = VLD(cA.z); rA3 = VLD(cA.w);
    rB0 = VLD(cB.x); rB1 = VLD(cB.y); rB2 = VLD(cB.z); rB3 = VLD(cB.w);
    rC0 = VLD(cC.x); rC1 = VLD(cC.y); rC2 = VLD(cC.z); rC3 = VLD(cC.w);
    rD0 = VLD(cD.x); rD1 = VLD(cD.y); rD2 = VLD(cD.z); rD3 = VLD(cD.w);
  }
  int q = 0;
  #define AGG_STEP(cX, cX2, r0, r1, r2, r3, LEAD)                       \
    do {                                                                \
      fmix2p(ax, ay, (unsigned)cX.x, r0);                               \
      fmix2p(ax, ay, (unsigned)cX.y, r1);                               \
      fmix2p(ax, ay, (unsigned)cX.z, r2);                               \
      fmix2p(ax, ay, (unsigned)cX.w, r3);                               \
      r0 = VLD(cX2.x); r1 = VLD(cX2.y);                                 \
      r2 = VLD(cX2.z); r3 = VLD(cX2.w);                                 \
      cX = cX2;                                                         \
      int ii = q + (LEAD); ii = ii <= qlast ? ii : qlast;               \
      cX2 = c4[ii];                                                     \
    } while (0)
  for (; q + 3 < nq; q += 4){
    AGG_STEP(cA, cA2, rA0,rA1,rA2,rA3, 8);
    AGG_STEP(cB, cB2, rB0,rB1,rB2,rB3, 9);
    AGG_STEP(cC, cC2, rC0,rC1,rC2,rC3, 10);
    AGG_STEP(cD, cD2, rD0,rD1,rD2,rD3, 11);
  }
  #undef AGG_STEP
  #undef VLD
  int rem = nq - q;   // 0..3 (wave-uniform)
  if (rem > 0){
    fmix2p(ax, ay, (unsigned)cA.x, rA0);
    fmix2p(ax, ay, (unsigned)cA.y, rA1);
    fmix2p(ax, ay, (unsigned)cA.z, rA2);
    fmix2p(ax, ay, (unsigned)cA.w, rA3);
  }
  if (rem > 1){
    fmix2p(ax, ay, (unsigned)cB.x, rB0);
    fmix2p(ax, ay, (unsigned)cB.y, rB1);
    fmix2p(ax, ay, (unsigned)cB.z, rB2);
    fmix2p(ax, ay, (unsigned)cB.w, rB3);
  }
  if (rem > 2){
    fmix2p(ax, ay, (unsigned)cC.x, rC0);
    fmix2p(ax, ay, (unsigned)cC.y, rC1);
    fmix2p(ax, ay, (unsigned)cC.z, rC2);
    fmix2p(ax, ay, (unsigned)cC.w, rC3);
  }
}

// ---- agg layer 1: t1 = A*hw (fp16 rows, fp32 accum) ------------------------
__global__ __launch_bounds__(256) void k_agg1(const int2* __restrict__ oe,
    const unsigned* __restrict__ csr, const float* __restrict__ dinv,
    const unsigned int* __restrict__ V, unsigned int* __restrict__ T){
  int grp, chunk; map_block(blockIdx.x, grp, chunk);
  int tid = threadIdx.x;
  int l = tid & 63;
  int wv = __builtin_amdgcn_readfirstlane(tid) >> 6;   // wave-uniform
  const char* Vb = (const char*)(V + (size_t)grp * (NN * 64));
  unsigned int* Tg = T + (size_t)grp * (NN * 64);
  int loff = l * 4;
  for (int it = 0; it < 4; ++it){
    int n = chunk * 16 + wv * 4 + it;
    float din = dinv[n];
    int2 ee = oe[n];
    unsigned sv = *(const unsigned*)(Vb + (unsigned)((n << 8) + loff));
    float ax = 0.f, ay = 0.f;
    fmix2s(ax, ay, din, sv);
    agg_edges(ee.x, ee.y, csr, Vb, loff, ax, ay);
    Tg[((size_t)n << 6) + l] =
        (unsigned)f2h(din * ax) | ((unsigned)f2h(din * ay) << 16);
  }
}

// ---- agg layer 2 + epilogue: out = tanh(A*t1 + srow*bb + b2) fp32 ----------
__global__ __launch_bounds__(256) void k_agg2(const int2* __restrict__ oe,
    const unsigned* __restrict__ csr, const float* __restrict__ dinv,
    const float* __restrict__ srow, const float* __restrict__ bb,
    const float* __restrict__ b2, const unsigned int* __restrict__ V,
    float* __restrict__ out){
  int grp, chunk; map_block(blockIdx.x, grp, chunk);
  int tid = threadIdx.x;
  int l = tid & 63;
  int wv = __builtin_amdgcn_readfirstlane(tid) >> 6;
  int p = l >> 4, fi = l & 15;
  const char* Vb = (const char*)(V + (size_t)grp * (NN * 64));
  int pg = grp * PG + p;
  float2 bbq = ((const float2*)bb)[fi];
  float2 b2q = ((const float2*)b2)[fi];
  float* outp = out + (size_t)pg * (NN * FF);
  int loff = l * 4;
  for (int it = 0; it < 4; ++it){
    int n = chunk * 16 + wv * 4 + it;
    float din = dinv[n];
    int2 ee = oe[n];
    unsigned sv = *(const unsigned*)(Vb + (unsigned)((n << 8) + loff));
    float ax = 0.f, ay = 0.f;
    fmix2s(ax, ay, din, sv);
    agg_edges(ee.x, ee.y, csr, Vb, loff, ax, ay);
    float sr = din * (din + srow[n]);   // srow reconstructed from scatter acc
    float2 o;
    o.x = tanhf(din * ax + sr * bbq.x + b2q.x);
    o.y = tanhf(din * ay + sr * bbq.y + b2q.y);
    ((float2*)(outp + (size_t)n * FF))[fi] = o;
  }
}

extern "C" void kernel_launch(void* const* d_in, const int* in_sizes, int n_in,
                              void* d_out, int out_size, void* d_ws, size_t ws_size,
                              hipStream_t stream){
  const float* x    = (const float*)d_in[0];
  const float* mask = (const float*)d_in[1];
  const int*   ei   = (const int*)d_in[2];
  const float* W1   = (const float*)d_in[3];
  const float* b1   = (const float*)d_in[4];
  const float* W2   = (const float*)d_in[5];
  const float* b2   = (const float*)d_in[6];
  float* out = (float*)d_out;
  const int E = in_sizes[2] / 2;   // 320000
  const int CSRCAP = E + 3 * NN + 64;  // padded-to-4 worst case + slack (entries)

  char* wsp = (char*)d_ws;
  auto alloc = [&](size_t bytes) -> char* {
    char* p = wsp; wsp += (bytes + 255) & ~(size_t)255; return p;
  };
  // zero-span buffers first (cnt..gtop zeroed by ONE memset)
  int*   cnt  = (int*)  alloc((size_t)NN * 4);
  int*   cur  = (int*)  alloc((size_t)NN * 4);
  float* srow = (float*)alloc((size_t)NN * 4);
  int*   gtop = (int*)  alloc(256);
  float* dinv = (float*)alloc((size_t)NN * 4);
  int2*  oe   = (int2*) alloc((size_t)NN * 8);
  float* W12  = (float*)alloc(33 * 32 * 4);
  float* bbv  = (float*)alloc(32 * 4);
  unsigned* csr = (unsigned*)alloc((size_t)CSRCAP * 4);
  const size_t per_group = (size_t)NN * 64 * 4;    // [n][4p][32f] fp16 = 2.56MB
  unsigned int* hw = (unsigned int*)alloc((size_t)NGRP * per_group);
  unsigned int* t1 = (unsigned int*)alloc((size_t)NGRP * per_group);

  size_t zspan = (size_t)((char*)dinv - (char*)cnt);
  hipMemsetAsync(cnt, 0, zspan, stream);               // cnt+cur+srow+gtop
  k_count  <<<(E + 255) / 256, 256, 0, stream>>>(ei + E, cnt, csr, CSRCAP, E);
  k_prep   <<<45, 256, 0, stream>>>(cnt, oe, dinv, gtop, W1, W2, b1, W12, bbv);
  k_scatter<<<(E + 255) / 256, 256, 0, stream>>>(ei, oe, cur, dinv, csr, srow, E);

  k_gemm1<<<dim3(40, 96), 256, 0, stream>>>(x, mask, W12, hw);
  k_agg1 <<<15000, 256, 0, stream>>>(oe, csr, dinv, hw, t1);
  k_agg2 <<<15000, 256, 0, stream>>>(oe, csr, dinv, srow, bbv, b2, t1, out);
}

// Round 9
// 490.533 us; speedup vs baseline: 1.5411x; 1.0106x over previous
//
#include <hip/hip_runtime.h>
#include <hip/hip_fp16.h>

#define NN 10000
#define FF 32
#define PG 4      // pairs per group
#define NGRP 24   // 96 pairs / PG

typedef __attribute__((ext_vector_type(2))) float f32x2;

__device__ __forceinline__ unsigned short f2h(float f){
  union { unsigned short s; _Float16 h; } c; c.h = (_Float16)f; return c.s;
}

// acc += w(f16, lo half of packed SGPR word) * halves of h. One VOP3P each.
// op_sel_hi:[1,1,0] marks S0 AND S1 as f16; op_sel[1] picks S1's half.
// S0 = wave-uniform packed csr word -> SGPR operand, zero VALU for weights.
__device__ __forceinline__ void fmix2p(float& ax, float& ay, unsigned wpk, unsigned h){
  asm("v_fma_mix_f32 %0, %2, %3, %0 op_sel_hi:[1,1,0]\n\t"
      "v_fma_mix_f32 %1, %2, %3, %1 op_sel:[0,1,0] op_sel_hi:[1,1,0]"
      : "+v"(ax), "+v"(ay) : "s"(wpk), "v"(h));
}
// f32 SGPR weight variant (self-loop dinv term).
__device__ __forceinline__ void fmix2s(float& ax, float& ay, float w, unsigned h){
  asm("v_fma_mix_f32 %0, %2, %3, %0 op_sel_hi:[0,1,0]\n\t"
      "v_fma_mix_f32 %1, %2, %3, %1 op_sel:[0,1,0] op_sel_hi:[0,1,0]"
      : "+v"(ax), "+v"(ay) : "s"(w), "v"(h));
}

// packed fp32 FMA for gemm1 (157 TF fp32 peak needs v_pk_fma_f32).
__device__ __forceinline__ void pkfma(f32x2& acc, f32x2 w, f32x2 x){
  asm("v_pk_fma_f32 %0, %1, %2, %0" : "+v"(acc) : "s"(w), "v"(x));
}

// ---- CSR build -------------------------------------------------------------
// csr entry (u32): (src << 16) | fp16(dinv[src]). Zeroed here: pad entries
// read row 0 with weight 0.0 -> harmless. 4 B/edge -> csr 1.4 MB, fits L2
// next to the 2.56 MB V slice.
__global__ void k_count(const int* __restrict__ dst, int* __restrict__ cnt,
                        unsigned* __restrict__ csr, int csrcap, int E){
  int e = blockIdx.x * 256 + threadIdx.x;
  if (e >= E) return;
  csr[e] = 0u;
  int e2 = e + E;
  if (e2 < csrcap) csr[e2] = 0u;
  atomicAdd(&cnt[dst[e]], 1);
}

// Parallel prep: offsets via unordered atomicAdd allocation (row order is
// irrelevant); stores {start,end}. Blocks 40..44 compute W12/bb.
__global__ __launch_bounds__(256) void k_prep(const int* __restrict__ cnt,
    int2* __restrict__ oe, float* __restrict__ dinv, int* __restrict__ gtop,
    const float* __restrict__ W1, const float* __restrict__ W2,
    const float* __restrict__ b1, float* __restrict__ W12, float* __restrict__ bb){
  int bx = blockIdx.x, tid = threadIdx.x;
  if (bx < 40){
    int i = bx * 256 + tid;
    if (i < NN){
      int c = cnt[i];
      int pad = (c + 3) & ~3;
      int start = atomicAdd(gtop, pad);
      oe[i] = make_int2(start, start + pad);
      dinv[i] = rsqrtf((float)(c + 1));
    }
  } else {
    int j = (bx - 40) * 256 + tid;
    if (j < 33 * 32){
      int k = j >> 5, c = j & 31;
      float s = 0.f;
      for (int m = 0; m < 64; ++m) s += W1[k * 64 + m] * W2[m * 32 + c];
      W12[j] = s;
    } else if (j < 33 * 32 + 32){
      int c = j - 33 * 32;
      float s = 0.f;
      for (int m = 0; m < 64; ++m) s += b1[m] * W2[m * 32 + c];
      bb[c] = s;
    }
  }
}

// Also accumulates srow_acc[d] = sum of dinv[src] (agg2 reconstructs
// srow = dinv*(dinv+acc)).
__global__ void k_scatter(const int* __restrict__ ei, const int2* __restrict__ oe,
                          int* __restrict__ cur, const float* __restrict__ dinv,
                          unsigned* __restrict__ csr, float* __restrict__ srow, int E){
  int e = blockIdx.x * 256 + threadIdx.x;
  if (e >= E) return;
  int s = ei[e], d = ei[E + e];
  float ds = dinv[s];
  int pos = oe[d].x + atomicAdd(&cur[d], 1);
  csr[pos] = ((unsigned)s << 16) | (unsigned)f2h(ds);
  atomicAdd(&srow[d], ds);
}

// ---- GEMM1: one thread = one (pg, node); packed-fp32 math ------------------
__global__ __launch_bounds__(256) void k_gemm1(const float* __restrict__ x,
    const float* __restrict__ mask, const float* __restrict__ W12,
    unsigned* __restrict__ hw){
  const int pg = blockIdx.y;                  // 0..95 (b*24+h)
  const int n  = blockIdx.x * 256 + threadIdx.x;
  const int grp = pg >> 2, p = pg & 3;
  const float mv = mask[pg];
  const f32x2* Wp = (const f32x2*)W12;        // [33][16] feature pairs
  f32x2 acc[16];
  #pragma unroll
  for (int qf = 0; qf < 16; ++qf){
    f32x2 w = Wp[32 * 16 + qf];               // mask row
    acc[qf].x = mv * w.x; acc[qf].y = mv * w.y;
  }
  if (n >= NN) return;
  const float4* xp = (const float4*)(x + (size_t)pg * (NN * FF) + (size_t)n * FF);
  float xv[32];
  #pragma unroll
  for (int i = 0; i < 8; ++i){
    float4 v = xp[i];
    xv[4*i]   = v.x; xv[4*i+1] = v.y;
    xv[4*i+2] = v.z; xv[4*i+3] = v.w;
  }
  #pragma unroll
  for (int k = 0; k < 32; ++k){
    f32x2 xk2; xk2.x = xv[k]; xk2.y = xv[k];
    #pragma unroll
    for (int qf = 0; qf < 16; ++qf) pkfma(acc[qf], Wp[k * 16 + qf], xk2);
  }
  unsigned* hwg = hw + (size_t)grp * (NN * 64) + ((size_t)n << 6) + (p << 4);
  #pragma unroll
  for (int j = 0; j < 4; ++j){
    uint4 u;
    u.x = (unsigned)f2h(acc[4*j+0].x) | ((unsigned)f2h(acc[4*j+0].y) << 16);
    u.y = (unsigned)f2h(acc[4*j+1].x) | ((unsigned)f2h(acc[4*j+1].y) << 16);
    u.z = (unsigned)f2h(acc[4*j+2].x) | ((unsigned)f2h(acc[4*j+2].y) << 16);
    u.w = (unsigned)f2h(acc[4*j+3].x) | ((unsigned)f2h(acc[4*j+3].y) << 16);
    ((uint4*)hwg)[j] = u;
  }
}

// ---- block->group mapping: pin each group to one XCD (blockIdx%8) ----------
__device__ __forceinline__ void map_block(int bx, int& grp, int& chunk){
  int r  = bx / 5000;       // 0..2
  int w8 = bx % 5000;
  grp   = r * 8 + (w8 & 7);
  chunk = w8 >> 3;          // 0..624
}

// ---- 4-deep pipelined edge accumulation, packed csr, BATCHED csr s_loads ---
// SMEM results are out-of-order w.r.t. lgkmcnt -> every s_load consumption
// drains ALL outstanding s_loads. r8 issued one s_load per STEP and consumed
// a 1-step-old result per STEP -> ~60-100 cy hidden stall per quad. Here the
// csr window is 3 stages (cX=q, cX2=q+4, cX3=q+8; 2 s_movs/step) and all 4
// s_loads issue as ONE batch at the body bottom (quads q+12..q+15), consumed
// as gather addresses 2 iterations (~260 cy) later. Any drain point now sees
// only >=1-iteration-old loads.
#define ROWB(w) ((((unsigned)(w)) >> 8) & 0xFFFF00u)
__device__ __forceinline__ void agg_edges(int e0, int e1,
    const unsigned* __restrict__ csr, const char* __restrict__ Vb, int loff,
    float& ax, float& ay){
  int nq = (e1 - e0) >> 2;
  if (nq <= 0) return;
  const int4* c4 = (const int4*)(csr + e0);   // 16 B per quad
  const int qlast = nq - 1;
  #define VLD(w) (*(const unsigned*)(Vb + (unsigned)(ROWB(w) + loff)))
  int4 cA, cB, cC, cD;          // csr quads q..q+3   (fmix source)
  int4 cA2, cB2, cC2, cD2;      // csr quads q+4..q+7 (gather-address source)
  int4 cA3, cB3, cC3, cD3;      // csr quads q+8..q+11 (in-flight window)
  unsigned rA0,rA1,rA2,rA3, rB0,rB1,rB2,rB3;
  unsigned rC0,rC1,rC2,rC3, rD0,rD1,rD2,rD3;
  {
    int i1 = 1<=qlast?1:qlast, i2 = 2<=qlast?2:qlast, i3 = 3<=qlast?3:qlast;
    cA = c4[0]; cB = c4[i1]; cC = c4[i2]; cD = c4[i3];
    int i4 = 4<=qlast?4:qlast, i5 = 5<=qlast?5:qlast;
    int i6 = 6<=qlast?6:qlast, i7 = 7<=qlast?7:qlast;
    cA2 = c4[i4]; cB2 = c4[i5]; cC2 = c4[i6]; cD2 = c4[i7];
    int i8 = 8<=qlast?8:qlast, i9 = 9<=qlast?9:qlast;
    int i10 = 10<=qlast?10:qlast, i11 = 11<=qlast?11:qlast;
    cA3 = c4[i8]; cB3 = c4[i9]; cC3 = c4[i10]; cD3 = c4[i11];
    rA0 = VLD(cA.x); rA1 = VLD(cA.y); rA2 = VLD(cA.z); rA3 = VLD(cA.w);
    rB0 = VLD(cB.x); rB1 = VLD(cB.y); rB2 = VLD(cB.z); rB3 = VLD(cB.w);
    rC0 = VLD(cC.x); rC1 = VLD(cC.y); rC2 = VLD(cC.z); rC3 = VLD(cC.w);
    rD0 = VLD(cD.x); rD1 = VLD(cD.y); rD2 = VLD(cD.z); rD3 = VLD(cD.w);
  }
  int q = 0;
  #define AGG_STEP(cX, cX2, cX3, r0, r1, r2, r3)                        \
    do {                                                                \
      fmix2p(ax, ay, (unsigned)cX.x, r0);                               \
      fmix2p(ax, ay, (unsigned)cX.y, r1);                               \
      fmix2p(ax, ay, (unsigned)cX.z, r2);                               \
      fmix2p(ax, ay, (unsigned)cX.w, r3);                               \
      r0 = VLD(cX2.x); r1 = VLD(cX2.y);                                 \
      r2 = VLD(cX2.z); r3 = VLD(cX2.w);                                 \
      cX = cX2; cX2 = cX3;                                              \
    } while (0)
  for (; q + 3 < nq; q += 4){
    AGG_STEP(cA, cA2, cA3, rA0,rA1,rA2,rA3);
    AGG_STEP(cB, cB2, cB3, rB0,rB1,rB2,rB3);
    AGG_STEP(cC, cC2, cC3, rC0,rC1,rC2,rC3);
    AGG_STEP(cD, cD2, cD3, rD0,rD1,rD2,rD3);
    int j0 = q+12 <= qlast ? q+12 : qlast;
    int j1 = q+13 <= qlast ? q+13 : qlast;
    int j2 = q+14 <= qlast ? q+14 : qlast;
    int j3 = q+15 <= qlast ? q+15 : qlast;
    cA3 = c4[j0]; cB3 = c4[j1]; cC3 = c4[j2]; cD3 = c4[j3];
  }
  #undef AGG_STEP
  #undef VLD
  int rem = nq - q;   // 0..3 (wave-uniform)
  if (rem > 0){
    fmix2p(ax, ay, (unsigned)cA.x, rA0);
    fmix2p(ax, ay, (unsigned)cA.y, rA1);
    fmix2p(ax, ay, (unsigned)cA.z, rA2);
    fmix2p(ax, ay, (unsigned)cA.w, rA3);
  }
  if (rem > 1){
    fmix2p(ax, ay, (unsigned)cB.x, rB0);
    fmix2p(ax, ay, (unsigned)cB.y, rB1);
    fmix2p(ax, ay, (unsigned)cB.z, rB2);
    fmix2p(ax, ay, (unsigned)cB.w, rB3);
  }
  if (rem > 2){
    fmix2p(ax, ay, (unsigned)cC.x, rC0);
    fmix2p(ax, ay, (unsigned)cC.y, rC1);
    fmix2p(ax, ay, (unsigned)cC.z, rC2);
    fmix2p(ax, ay, (unsigned)cC.w, rC3);
  }
}

// ---- agg layer 1: t1 = A*hw (fp16 rows, fp32 accum) ------------------------
__global__ __launch_bounds__(256) void k_agg1(const int2* __restrict__ oe,
    const unsigned* __restrict__ csr, const float* __restrict__ dinv,
    const unsigned int* __restrict__ V, unsigned int* __restrict__ T){
  int grp, chunk; map_block(blockIdx.x, grp, chunk);
  int tid = threadIdx.x;
  int l = tid & 63;
  int wv = __builtin_amdgcn_readfirstlane(tid) >> 6;   // wave-uniform
  const char* Vb = (const char*)(V + (size_t)grp * (NN * 64));
  unsigned int* Tg = T + (size_t)grp * (NN * 64);
  int loff = l * 4;
  for (int it = 0; it < 4; ++it){
    int n = chunk * 16 + wv * 4 + it;
    float din = dinv[n];
    int2 ee = oe[n];
    unsigned sv = *(const unsigned*)(Vb + (unsigned)((n << 8) + loff));
    float ax = 0.f, ay = 0.f;
    fmix2s(ax, ay, din, sv);
    agg_edges(ee.x, ee.y, csr, Vb, loff, ax, ay);
    Tg[((size_t)n << 6) + l] =
        (unsigned)f2h(din * ax) | ((unsigned)f2h(din * ay) << 16);
  }
}

// ---- agg layer 2 + epilogue: out = tanh(A*t1 + srow*bb + b2) fp32 ----------
__global__ __launch_bounds__(256) void k_agg2(const int2* __restrict__ oe,
    const unsigned* __restrict__ csr, const float* __restrict__ dinv,
    const float* __restrict__ srow, const float* __restrict__ bb,
    const float* __restrict__ b2, const unsigned int* __restrict__ V,
    float* __restrict__ out){
  int grp, chunk; map_block(blockIdx.x, grp, chunk);
  int tid = threadIdx.x;
  int l = tid & 63;
  int wv = __builtin_amdgcn_readfirstlane(tid) >> 6;
  int p = l >> 4, fi = l & 15;
  const char* Vb = (const char*)(V + (size_t)grp * (NN * 64));
  int pg = grp * PG + p;
  float2 bbq = ((const float2*)bb)[fi];
  float2 b2q = ((const float2*)b2)[fi];
  float* outp = out + (size_t)pg * (NN * FF);
  int loff = l * 4;
  for (int it = 0; it < 4; ++it){
    int n = chunk * 16 + wv * 4 + it;
    float din = dinv[n];
    int2 ee = oe[n];
    unsigned sv = *(const unsigned*)(Vb + (unsigned)((n << 8) + loff));
    float ax = 0.f, ay = 0.f;
    fmix2s(ax, ay, din, sv);
    agg_edges(ee.x, ee.y, csr, Vb, loff, ax, ay);
    float sr = din * (din + srow[n]);   // srow reconstructed from scatter acc
    float2 o;
    o.x = tanhf(din * ax + sr * bbq.x + b2q.x);
    o.y = tanhf(din * ay + sr * bbq.y + b2q.y);
    ((float2*)(outp + (size_t)n * FF))[fi] = o;
  }
}

extern "C" void kernel_launch(void* const* d_in, const int* in_sizes, int n_in,
                              void* d_out, int out_size, void* d_ws, size_t ws_size,
                              hipStream_t stream){
  const float* x    = (const float*)d_in[0];
  const float* mask = (const float*)d_in[1];
  const int*   ei   = (const int*)d_in[2];
  const float* W1   = (const float*)d_in[3];
  const float* b1   = (const float*)d_in[4];
  const float* W2   = (const float*)d_in[5];
  const float* b2   = (const float*)d_in[6];
  float* out = (float*)d_out;
  const int E = in_sizes[2] / 2;   // 320000
  const int CSRCAP = E + 3 * NN + 64;  // padded-to-4 worst case + slack (entries)

  char* wsp = (char*)d_ws;
  auto alloc = [&](size_t bytes) -> char* {
    char* p = wsp; wsp += (bytes + 255) & ~(size_t)255; return p;
  };
  // zero-span buffers first (cnt..gtop zeroed by ONE memset)
  int*   cnt  = (int*)  alloc((size_t)NN * 4);
  int*   cur  = (int*)  alloc((size_t)NN * 4);
  float* srow = (float*)alloc((size_t)NN * 4);
  int*   gtop = (int*)  alloc(256);
  float* dinv = (float*)alloc((size_t)NN * 4);
  int2*  oe   = (int2*) alloc((size_t)NN * 8);
  float* W12  = (float*)alloc(33 * 32 * 4);
  float* bbv  = (float*)alloc(32 * 4);
  unsigned* csr = (unsigned*)alloc((size_t)CSRCAP * 4);
  const size_t per_group = (size_t)NN * 64 * 4;    // [n][4p][32f] fp16 = 2.56MB
  unsigned int* hw = (unsigned int*)alloc((size_t)NGRP * per_group);
  unsigned int* t1 = (unsigned int*)alloc((size_t)NGRP * per_group);

  size_t zspan = (size_t)((char*)dinv - (char*)cnt);
  hipMemsetAsync(cnt, 0, zspan, stream);               // cnt+cur+srow+gtop
  k_count  <<<(E + 255) / 256, 256, 0, stream>>>(ei + E, cnt, csr, CSRCAP, E);
  k_prep   <<<45, 256, 0, stream>>>(cnt, oe, dinv, gtop, W1, W2, b1, W12, bbv);
  k_scatter<<<(E + 255) / 256, 256, 0, stream>>>(ei, oe, cur, dinv, csr, srow, E);

  k_gemm1<<<dim3(40, 96), 256, 0, stream>>>(x, mask, W12, hw);
  k_agg1 <<<15000, 256, 0, stream>>>(oe, csr, dinv, hw, t1);
  k_agg2 <<<15000, 256, 0, stream>>>(oe, csr, dinv, srow, bbv, b2, t1, out);
}